// Round 3
// baseline (34.783 us; speedup 1.0000x reference)
//
#include <hip/hip_runtime.h>

#define HH 48
#define WW 48
#define HW 2304   // 48*48
#define NB 8      // N
#define CB 4      // COLOR
#define TB 3      // RGB

// pred_img_i[b,n,t,y,x] = 0.25 * sum_c sum_s kw[b,n,s,t,y,x] *
//     sum_{i,j in KxK} c1[b,n,cur_s+i,c,t,y,x]*c2[b,n,cur_s+j,c,t,y,x]
//                      * F[b,n,c, y+i+p_s-3, x+j+p_s-3]
// s=0:K=7,cur=9  s=1:K=5,cur=4  s=2:K=3,cur=1  s=3:K=1,cur=0

// ---- main kernel: one thread per (b,n,c,t, pixel-PAIR); float2 traffic ----
__global__ __launch_bounds__(256) void kconv2(
    const float* __restrict__ frames,   // (4, 8, 4, 48, 48)
    const float* __restrict__ core,     // (4, 3072, 48, 48)  ch=((n*32+q)*4+c)*3+t
    const float* __restrict__ kw,       // (4, 8, 4, 3, 48, 48)
    float* __restrict__ part)           // (4, 8, 4, 3, 2304) partials
{
    const int tid = blockIdx.x * blockDim.x + threadIdx.x;  // 442368 total
    const int pp  = tid % (HW / 2);
    int rem = tid / (HW / 2);
    const int t = rem % TB; rem /= TB;
    const int c = rem % CB; rem /= CB;
    const int n = rem % NB;
    const int b = rem / NB;
    const int pix0 = pp * 2;            // even; both pixels on same row
    const int x0 = pix0 % WW;
    const int y  = pix0 / WW;

    // kw[b,n,s,t,pix0..pix0+1] for s=0..3
    const float* kwf = kw + ((size_t)(b * NB + n) * 12 + t) * HW + pix0;
    const float2 kw0 = *(const float2*)(kwf);
    const float2 kw1 = *(const float2*)(kwf + (size_t)3 * HW);
    const float2 kw2 = *(const float2*)(kwf + (size_t)6 * HW);
    const float2 kw3 = *(const float2*)(kwf + (size_t)9 * HW);

    // 32 float2 core values for this (b,n,c,t) pixel pair
    const float* cp = core + ((size_t)b * 3072 + (size_t)((n * 32) * CB + c) * 3 + t) * HW + pix0;
    float2 a2[16], b2[16];
    #pragma unroll
    for (int q = 0; q < 16; ++q) {
        a2[q] = *(const float2*)(cp + (size_t)(q * 12) * HW);
        b2[q] = *(const float2*)(cp + (size_t)((q + 16) * 12) * HW);
    }

    const float* fb = frames + ((size_t)(b * NB + n) * CB + c) * HW;

    float r7x = 0.f, r7y = 0.f, r5x = 0.f, r5y = 0.f;
    float r3x = 0.f, r3y = 0.f, r1x = 0.f, r1y = 0.f;

    #pragma unroll
    for (int i = 0; i < 7; ++i) {
        const int yy = y + i - 3;
        const bool yok = (yy >= 0) & (yy < HH);
        const int yyc = min(max(yy, 0), HH - 1);
        const float* frow = fb + yyc * WW;
        float fp[8];
        #pragma unroll
        for (int j = 0; j < 8; ++j) {
            const int xx = x0 + j - 3;
            const bool ok = yok & (xx >= 0) & (xx < WW);
            const int xxc = min(max(xx, 0), WW - 1);
            const float v = frow[xxc];          // branchless clamped load
            fp[j] = ok ? v : 0.f;
        }
        // 7-tap
        {
            float i0 = 0.f, i1 = 0.f;
            #pragma unroll
            for (int j = 0; j < 7; ++j) {
                i0 = fmaf(b2[9 + j].x, fp[j],     i0);
                i1 = fmaf(b2[9 + j].y, fp[j + 1], i1);
            }
            r7x = fmaf(a2[9 + i].x, i0, r7x);
            r7y = fmaf(a2[9 + i].y, i1, r7y);
        }
        // 5-tap (rows 1..5)
        if (i >= 1 && i <= 5) {
            float i0 = 0.f, i1 = 0.f;
            #pragma unroll
            for (int j = 0; j < 5; ++j) {
                i0 = fmaf(b2[4 + j].x, fp[1 + j], i0);
                i1 = fmaf(b2[4 + j].y, fp[2 + j], i1);
            }
            r5x = fmaf(a2[4 + i - 1].x, i0, r5x);
            r5y = fmaf(a2[4 + i - 1].y, i1, r5y);
        }
        // 3-tap (rows 2..4)
        if (i >= 2 && i <= 4) {
            float i0 = 0.f, i1 = 0.f;
            #pragma unroll
            for (int j = 0; j < 3; ++j) {
                i0 = fmaf(b2[1 + j].x, fp[2 + j], i0);
                i1 = fmaf(b2[1 + j].y, fp[3 + j], i1);
            }
            r3x = fmaf(a2[1 + i - 2].x, i0, r3x);
            r3y = fmaf(a2[1 + i - 2].y, i1, r3y);
        }
        // 1-tap (row 3)
        if (i == 3) {
            r1x = a2[0].x * b2[0].x * fp[3];
            r1y = a2[0].y * b2[0].y * fp[4];
        }
    }

    const float p0 = fmaf(kw0.x, r7x, fmaf(kw1.x, r5x, fmaf(kw2.x, r3x, kw3.x * r1x)));
    const float p1 = fmaf(kw0.y, r7y, fmaf(kw1.y, r5y, fmaf(kw2.y, r3y, kw3.y * r1y)));
    *(float2*)(part + (size_t)2 * tid) = make_float2(p0, p1);
}

// pred_img_i[b,n,t,pix] = 0.25 * sum_c part[b,n,c,t,pix]   (float2 per thread)
__global__ __launch_bounds__(256) void reduce_c2(
    const float* __restrict__ part, float* __restrict__ out)
{
    const int tid = blockIdx.x * blockDim.x + threadIdx.x;  // 110592
    const int pr = tid % (TB * HW / 2);
    const int bn = tid / (TB * HW / 2);
    const float* p = part + (size_t)bn * CB * TB * HW + (size_t)2 * pr;
    const float2 v0 = *(const float2*)(p);
    const float2 v1 = *(const float2*)(p + (size_t)TB * HW);
    const float2 v2 = *(const float2*)(p + (size_t)2 * TB * HW);
    const float2 v3 = *(const float2*)(p + (size_t)3 * TB * HW);
    float2 r;
    r.x = 0.25f * (v0.x + v1.x + v2.x + v3.x);
    r.y = 0.25f * (v0.y + v1.y + v2.y + v3.y);
    *(float2*)(out + (size_t)2 * tid) = r;
}

// pred_img[b,t,pix] = mean_n pred_img_i[b,n,t,pix]   (float2 per thread)
__global__ __launch_bounds__(256) void mean2(
    const float* __restrict__ pii, float* __restrict__ pm)
{
    const int tid = blockIdx.x * blockDim.x + threadIdx.x;  // 13824
    if (tid >= 4 * TB * HW / 2) return;
    const int pr = tid % (TB * HW / 2);
    const int b = tid / (TB * HW / 2);
    float sx = 0.f, sy = 0.f;
    #pragma unroll
    for (int n = 0; n < NB; ++n) {
        const float2 v = *(const float2*)(pii + (size_t)((b * NB + n) * TB) * HW + (size_t)2 * pr);
        sx += v.x; sy += v.y;
    }
    *(float2*)(pm + (size_t)2 * tid) = make_float2(sx * 0.125f, sy * 0.125f);
}

// ---- fallback monolithic kernel (used only if ws too small) ----
__global__ __launch_bounds__(256) void kconv_kernel(
    const float* __restrict__ frames, const float* __restrict__ core,
    const float* __restrict__ kw, float* __restrict__ out)
{
    const int tid = blockIdx.x * blockDim.x + threadIdx.x;
    const int x = tid % WW;
    const int y = (tid / WW) % HH;
    const int n = (tid / HW) % NB;
    const int b = tid / (HW * NB);
    const int pix = y * WW + x;

    float kwv[4][3];
    {
        const float* kwp = kw + (size_t)((b * NB + n) * 12) * HW + pix;
        #pragma unroll
        for (int s = 0; s < 4; ++s)
            #pragma unroll
            for (int t = 0; t < TB; ++t)
                kwv[s][t] = kwp[(size_t)(s * 3 + t) * HW];
    }
    float acc[TB] = {0.f, 0.f, 0.f};
    const float* fbase = frames + (size_t)((b * NB + n) * CB) * HW;
    const float* cbase = core + (size_t)b * 3072 * HW + pix;
    for (int c = 0; c < CB; ++c) {
        float fpv[49];
        #pragma unroll
        for (int i = 0; i < 7; ++i) {
            const int yy = y + i - 3;
            #pragma unroll
            for (int j = 0; j < 7; ++j) {
                const int xx = x + j - 3;
                const bool ok = (yy >= 0) & (yy < HH) & (xx >= 0) & (xx < WW);
                fpv[i * 7 + j] = ok ? fbase[(size_t)c * HW + yy * WW + xx] : 0.f;
            }
        }
        #pragma unroll
        for (int t = 0; t < TB; ++t) {
            float a[16], bv[16];
            const float* cp = cbase + (size_t)(((n * 32) * CB + c) * 3 + t) * HW;
            #pragma unroll
            for (int q = 0; q < 16; ++q) {
                a[q]  = cp[(size_t)(q * 12) * HW];
                bv[q] = cp[(size_t)((q + 16) * 12) * HW];
            }
            float tot = 0.f;
            {
                float r = 0.f;
                #pragma unroll
                for (int i = 0; i < 7; ++i) {
                    float inner = 0.f;
                    #pragma unroll
                    for (int j = 0; j < 7; ++j) inner = fmaf(bv[9 + j], fpv[i * 7 + j], inner);
                    r = fmaf(a[9 + i], inner, r);
                }
                tot = fmaf(kwv[0][t], r, tot);
            }
            {
                float r = 0.f;
                #pragma unroll
                for (int i = 0; i < 5; ++i) {
                    float inner = 0.f;
                    #pragma unroll
                    for (int j = 0; j < 5; ++j) inner = fmaf(bv[4 + j], fpv[(1 + i) * 7 + 1 + j], inner);
                    r = fmaf(a[4 + i], inner, r);
                }
                tot = fmaf(kwv[1][t], r, tot);
            }
            {
                float r = 0.f;
                #pragma unroll
                for (int i = 0; i < 3; ++i) {
                    float inner = 0.f;
                    #pragma unroll
                    for (int j = 0; j < 3; ++j) inner = fmaf(bv[1 + j], fpv[(2 + i) * 7 + 2 + j], inner);
                    r = fmaf(a[1 + i], inner, r);
                }
                tot = fmaf(kwv[2][t], r, tot);
            }
            tot = fmaf(kwv[3][t], a[0] * bv[0] * fpv[3 * 7 + 3], tot);
            acc[t] += 0.25f * tot;
        }
    }
    float* op = out + (size_t)((b * NB + n) * TB) * HW + pix;
    op[0] = acc[0]; op[HW] = acc[1]; op[2 * HW] = acc[2];
}

extern "C" void kernel_launch(void* const* d_in, const int* in_sizes, int n_in,
                              void* d_out, int out_size, void* d_ws, size_t ws_size,
                              hipStream_t stream) {
    const float* frames = (const float*)d_in[0];
    const float* core   = (const float*)d_in[1];
    const float* kw     = (const float*)d_in[2];
    float* out = (float*)d_out;                 // pred_img_i: 221184 floats
    float* pm  = out + 4 * NB * TB * HW;        // pred_img:   27648 floats

    const size_t part_elems = (size_t)4 * NB * CB * TB * HW;  // 884736
    if (ws_size >= part_elems * sizeof(float)) {
        float* part = (float*)d_ws;
        kconv2<<<(int)(part_elems / 2 / 256), 256, 0, stream>>>(frames, core, kw, part);
        reduce_c2<<<(4 * NB * TB * HW / 2) / 256, 256, 0, stream>>>(part, out);
    } else {
        kconv_kernel<<<(4 * NB * HW) / 256, 256, 0, stream>>>(frames, core, kw, out);
    }
    mean2<<<(4 * TB * HW / 2 + 255) / 256, 256, 0, stream>>>(out, pm);
}

// Round 4
// 32.089 us; speedup vs baseline: 1.0839x; 1.0839x over previous
//
#include <hip/hip_runtime.h>

#define HH 48
#define WW 48
#define HW 2304   // 48*48
#define NB 8      // N
#define CB 4      // COLOR
#define TB 3      // RGB

// pred_img_i[b,n,t,y,x] = 0.25 * sum_c sum_s kw[b,n,s,t,y,x] *
//     sum_{i,j in KxK} c1[b,n,cur_s+i,c,t,y,x]*c2[b,n,cur_s+j,c,t,y,x]
//                      * F[b,n,c, y+i+p_s-3, x+j+p_s-3]
// s=0:K=7,cur=9  s=1:K=5,cur=4  s=2:K=3,cur=1  s=3:K=1,cur=0
//
// Block = 192 threads = 4 colors x 48 pixels (one image row of one (b,n)).
// Each thread: 7x7 frame patch in regs (loaded once), loop t {32 core loads,
// 4 kw loads, separable FMA}, partial -> LDS; LDS reduce over c -> pred_img_i.

__global__ __launch_bounds__(192) void kconv_fused(
    const float* __restrict__ frames,   // (4, 8, 4, 48, 48)
    const float* __restrict__ core,     // (4, 3072, 48, 48)  ch=((n*32+q)*4+c)*3+t
    const float* __restrict__ kw,       // (4, 8, 4, 3, 48, 48)
    float* __restrict__ out)            // pred_img_i (4, 8, 3, 48, 48)
{
    const int bid = blockIdx.x;         // 4*8*48 = 1536
    const int y = bid % HH;
    const int n = (bid / HH) % NB;
    const int b = bid / (HH * NB);
    const int tidx = threadIdx.x;       // 0..191
    const int c = tidx / WW;            // 0..3
    const int x = tidx % WW;            // 0..47
    const int pix = y * WW + x;

    __shared__ float lds[CB][TB][WW];   // 2304 B

    // 7x7 zero-padded frame patch, loaded once, kept in registers
    const float* fb = frames + ((size_t)(b * NB + n) * CB + c) * HW;
    float fp[49];
    #pragma unroll
    for (int i = 0; i < 7; ++i) {
        const int yy = y + i - 3;
        const bool yok = (yy >= 0) & (yy < HH);
        const int yyc = min(max(yy, 0), HH - 1);
        #pragma unroll
        for (int j = 0; j < 7; ++j) {
            const int xx = x + j - 3;
            const bool ok = yok & (xx >= 0) & (xx < WW);
            const int xxc = min(max(xx, 0), WW - 1);
            const float v = fb[yyc * WW + xxc];   // branchless clamped load
            fp[i * 7 + j] = ok ? v : 0.f;
        }
    }

    const float* cbase = core + ((size_t)b * 3072 + (size_t)(n * 32 * CB + c) * 3) * HW + pix;
    const float* kwbase = kw + (size_t)(b * NB + n) * 12 * HW + pix;

    #pragma unroll
    for (int t = 0; t < TB; ++t) {
        // 32 core values for this (b,n,c,t,pix)
        const float* cp = cbase + (size_t)t * HW;
        float a[16], bv[16];
        #pragma unroll
        for (int q = 0; q < 16; ++q) {
            a[q]  = cp[(size_t)(q * 12) * HW];
            bv[q] = cp[(size_t)((q + 16) * 12) * HW];
        }

        float r7 = 0.f, r5 = 0.f, r3 = 0.f;
        #pragma unroll
        for (int i = 0; i < 7; ++i) {
            float in7 = 0.f;
            #pragma unroll
            for (int j = 0; j < 7; ++j) in7 = fmaf(bv[9 + j], fp[i * 7 + j], in7);
            r7 = fmaf(a[9 + i], in7, r7);
        }
        #pragma unroll
        for (int i = 0; i < 5; ++i) {
            float in5 = 0.f;
            #pragma unroll
            for (int j = 0; j < 5; ++j) in5 = fmaf(bv[4 + j], fp[(1 + i) * 7 + 1 + j], in5);
            r5 = fmaf(a[4 + i], in5, r5);
        }
        #pragma unroll
        for (int i = 0; i < 3; ++i) {
            float in3 = 0.f;
            #pragma unroll
            for (int j = 0; j < 3; ++j) in3 = fmaf(bv[1 + j], fp[(2 + i) * 7 + 2 + j], in3);
            r3 = fmaf(a[1 + i], in3, r3);
        }
        const float r1 = a[0] * bv[0] * fp[24];

        const float kw0 = kwbase[(size_t)(0 + t) * HW];
        const float kw1 = kwbase[(size_t)(3 + t) * HW];
        const float kw2 = kwbase[(size_t)(6 + t) * HW];
        const float kw3 = kwbase[(size_t)(9 + t) * HW];

        lds[c][t][x] = fmaf(kw0, r7, fmaf(kw1, r5, fmaf(kw2, r3, kw3 * r1)));
    }

    __syncthreads();

    // reduce over c: threads 0..143 -> (t, x)
    if (tidx < TB * WW) {
        const int t = tidx / WW;
        const int xo = tidx % WW;
        const float s = lds[0][t][xo] + lds[1][t][xo] + lds[2][t][xo] + lds[3][t][xo];
        out[((size_t)(b * NB + n) * TB + t) * HW + y * WW + xo] = 0.25f * s;
    }
}

// pred_img[b,t,pix] = mean_n pred_img_i[b,n,t,pix]   (float2 per thread)
__global__ __launch_bounds__(256) void mean2(
    const float* __restrict__ pii, float* __restrict__ pm)
{
    const int tid = blockIdx.x * blockDim.x + threadIdx.x;  // 13824
    if (tid >= 4 * TB * HW / 2) return;
    const int pr = tid % (TB * HW / 2);
    const int b = tid / (TB * HW / 2);
    float sx = 0.f, sy = 0.f;
    #pragma unroll
    for (int n = 0; n < NB; ++n) {
        const float2 v = *(const float2*)(pii + (size_t)((b * NB + n) * TB) * HW + (size_t)2 * pr);
        sx += v.x; sy += v.y;
    }
    *(float2*)(pm + (size_t)2 * tid) = make_float2(sx * 0.125f, sy * 0.125f);
}

extern "C" void kernel_launch(void* const* d_in, const int* in_sizes, int n_in,
                              void* d_out, int out_size, void* d_ws, size_t ws_size,
                              hipStream_t stream) {
    const float* frames = (const float*)d_in[0];
    const float* core   = (const float*)d_in[1];
    const float* kw     = (const float*)d_in[2];
    float* out = (float*)d_out;                 // pred_img_i: 221184 floats
    float* pm  = out + 4 * NB * TB * HW;        // pred_img:   27648 floats

    kconv_fused<<<4 * NB * HH, 192, 0, stream>>>(frames, core, kw, out);
    mean2<<<(4 * TB * HW / 2 + 255) / 256, 256, 0, stream>>>(out, pm);
}